// Round 2
// baseline (889.291 us; speedup 1.0000x reference)
//
#include <hip/hip_runtime.h>
#include <hip/hip_bf16.h>

// MHA block for MI355X: fp16 hi/lo split-precision MFMA everywhere.
// Pipeline: Qp/Kp = GEMM(hi/lo out) ; Vp = GEMM(f32) ; vtrans -> Vt hi/lo ;
// flash attention (swapped QK^T, online softmax) ; output GEMM -> d_out.

typedef _Float16 h8 __attribute__((ext_vector_type(8)));
typedef _Float16 h4 __attribute__((ext_vector_type(4)));
typedef float f32x4 __attribute__((ext_vector_type(4)));
typedef float f32x16 __attribute__((ext_vector_type(16)));

#define S_LEN 2048
#define DM 1024
#define DK 64

struct H2 { _Float16 h, l; };
__device__ __forceinline__ H2 split2(float v) {
  H2 r; r.h = (_Float16)v; r.l = (_Float16)(v - (float)r.h); return r;
}
__device__ __forceinline__ unsigned int pack2(float a, float b) {
  union { _Float16 h[2]; unsigned int u; } x;
  x.h[0] = (_Float16)a; x.h[1] = (_Float16)b;
  return x.u;
}

// Y[M=8192, N=1024] = X[8192,1024] @ W[1024,1024]^T + bias
// OUT_MODE 0: write hi/lo fp16 pair; 1: write fp32.
template<int OUT_MODE>
__global__ __launch_bounds__(256)
void gemm_xwT(const float* __restrict__ X, const float* __restrict__ W,
              const float* __restrict__ bias,
              _Float16* __restrict__ Yhi, _Float16* __restrict__ Ylo,
              float* __restrict__ Yf) {
  __shared__ _Float16 Ah[128 * 32], Al[128 * 32], Bh[128 * 32], Bl[128 * 32];
  const int tid = threadIdx.x;
  const int m0 = blockIdx.x * 128, n0 = blockIdx.y * 128;
  const int wid = tid >> 6, lane = tid & 63;
  const int wm = (wid >> 1) * 64, wn = (wid & 1) * 64;
  const int l15 = lane & 15, lg = lane >> 4;
  f32x4 acc[4][4] = {};
  for (int kt = 0; kt < 32; ++kt) {
    const int k0 = kt * 32;
#pragma unroll
    for (int u = 0; u < 4; ++u) {
      const int f = u * 256 + tid;
      const int row = f >> 3, c4 = (f & 7) * 4;
      const float4 xa = *(const float4*)&X[(size_t)(m0 + row) * DM + k0 + c4];
      const float4 xb = *(const float4*)&W[(size_t)(n0 + row) * DM + k0 + c4];
      h4 ah, al, bh, bl;
      H2 t0;
      t0 = split2(xa.x); ah[0] = t0.h; al[0] = t0.l;
      t0 = split2(xa.y); ah[1] = t0.h; al[1] = t0.l;
      t0 = split2(xa.z); ah[2] = t0.h; al[2] = t0.l;
      t0 = split2(xa.w); ah[3] = t0.h; al[3] = t0.l;
      t0 = split2(xb.x); bh[0] = t0.h; bl[0] = t0.l;
      t0 = split2(xb.y); bh[1] = t0.h; bl[1] = t0.l;
      t0 = split2(xb.z); bh[2] = t0.h; bl[2] = t0.l;
      t0 = split2(xb.w); bh[3] = t0.h; bl[3] = t0.l;
      *(h4*)&Ah[row * 32 + c4] = ah;
      *(h4*)&Al[row * 32 + c4] = al;
      *(h4*)&Bh[row * 32 + c4] = bh;
      *(h4*)&Bl[row * 32 + c4] = bl;
    }
    __syncthreads();
    h8 a_h[4], a_l[4], b_h[4], b_l[4];
#pragma unroll
    for (int i = 0; i < 4; ++i) {
      const int ra = (wm + i * 16 + l15) * 32 + lg * 8;
      const int rb = (wn + i * 16 + l15) * 32 + lg * 8;
      a_h[i] = *(const h8*)&Ah[ra];
      a_l[i] = *(const h8*)&Al[ra];
      b_h[i] = *(const h8*)&Bh[rb];
      b_l[i] = *(const h8*)&Bl[rb];
    }
#pragma unroll
    for (int mi = 0; mi < 4; ++mi)
#pragma unroll
      for (int ni = 0; ni < 4; ++ni) {
        acc[mi][ni] = __builtin_amdgcn_mfma_f32_16x16x32_f16(a_h[mi], b_h[ni], acc[mi][ni], 0, 0, 0);
        acc[mi][ni] = __builtin_amdgcn_mfma_f32_16x16x32_f16(a_h[mi], b_l[ni], acc[mi][ni], 0, 0, 0);
        acc[mi][ni] = __builtin_amdgcn_mfma_f32_16x16x32_f16(a_l[mi], b_h[ni], acc[mi][ni], 0, 0, 0);
      }
    __syncthreads();
  }
#pragma unroll
  for (int mi = 0; mi < 4; ++mi)
#pragma unroll
    for (int ni = 0; ni < 4; ++ni)
#pragma unroll
      for (int j = 0; j < 4; ++j) {
        const int rg = m0 + wm + mi * 16 + lg * 4 + j;  // C/D: row=(lane>>4)*4+reg
        const int cg = n0 + wn + ni * 16 + l15;         // col=lane&15
        const float v = acc[mi][ni][j] + bias[cg];
        if constexpr (OUT_MODE == 0) {
          H2 s = split2(v);
          Yhi[(size_t)rg * DM + cg] = s.h;
          Ylo[(size_t)rg * DM + cg] = s.l;
        } else {
          Yf[(size_t)rg * DM + cg] = v;
        }
      }
}

// Vp [B*S, DM] f32 -> Vt hi/lo [bh][d(64)][s(2048)] fp16
__global__ __launch_bounds__(256)
void mha_vtrans(const float* __restrict__ Vp,
                _Float16* __restrict__ Vthi, _Float16* __restrict__ Vtlo) {
  __shared__ float tile[64 * 65];
  const int bh = blockIdx.y, s0 = blockIdx.x * 64;
  const int b = bh >> 4, h = bh & 15;
  const int t = threadIdx.x;
  const int row = t >> 2, cg = (t & 3) * 16;
  const size_t inbase = ((size_t)(b * S_LEN + s0 + row)) * DM + h * DK + cg;
#pragma unroll
  for (int i = 0; i < 4; ++i) {
    const float4 v = *(const float4*)&Vp[inbase + i * 4];
    tile[row * 65 + cg + i * 4 + 0] = v.x;
    tile[row * 65 + cg + i * 4 + 1] = v.y;
    tile[row * 65 + cg + i * 4 + 2] = v.z;
    tile[row * 65 + cg + i * 4 + 3] = v.w;
  }
  __syncthreads();
  const int drow = t >> 2, sg = (t & 3) * 16;
  h8 hv0, hv1, lv0, lv1;
#pragma unroll
  for (int i = 0; i < 8; ++i) {
    H2 a = split2(tile[(sg + i) * 65 + drow]);
    hv0[i] = a.h; lv0[i] = a.l;
    H2 c = split2(tile[(sg + 8 + i) * 65 + drow]);
    hv1[i] = c.h; lv1[i] = c.l;
  }
  const size_t ob = ((size_t)bh * DK + drow) * S_LEN + s0 + sg;
  *(h8*)&Vthi[ob] = hv0;
  *(h8*)&Vthi[ob + 8] = hv1;
  *(h8*)&Vtlo[ob] = lv0;
  *(h8*)&Vtlo[ob + 8] = lv1;
}

// Flash attention: 1 wave per 32 q-rows per head. Swapped QK^T (S^T = K.Q^T)
// so each lane owns one q-row; online softmax in-register; PV via A=V^T.
__global__ __launch_bounds__(64)
void mha_attn(const _Float16* __restrict__ Qhi, const _Float16* __restrict__ Qlo,
              const _Float16* __restrict__ Khi, const _Float16* __restrict__ Klo,
              const _Float16* __restrict__ Vthi, const _Float16* __restrict__ Vtlo,
              float* __restrict__ O) {
  const int lane = threadIdx.x;
  const int l31 = lane & 31, hi = lane >> 5;
  const int qt = blockIdx.x, q0 = qt * 32;
  const int bh = blockIdx.y, b = bh >> 4, h = bh & 15;
  const size_t rowbase = (size_t)b * S_LEN * DM + h * DK;
  h8 qh[4], ql[4];
#pragma unroll
  for (int ks = 0; ks < 4; ++ks) {
    const size_t off = rowbase + (size_t)(q0 + l31) * DM + ks * 16 + hi * 8;
    qh[ks] = *(const h8*)&Qhi[off];
    ql[ks] = *(const h8*)&Qlo[off];
  }
  f32x16 po0 = {}, po1 = {};
  float m = -1e30f, l = 0.0f;
  const size_t vbase = (size_t)bh * DK * S_LEN;
  for (int t = 0; t <= qt; ++t) {
    const int c0 = t * 32;
    f32x16 sA = {}, sB = {};
#pragma unroll
    for (int ks = 0; ks < 4; ++ks) {
      const size_t koff = rowbase + (size_t)(c0 + l31) * DM + ks * 16 + hi * 8;
      const h8 kh = *(const h8*)&Khi[koff];
      const h8 kl = *(const h8*)&Klo[koff];
      sA = __builtin_amdgcn_mfma_f32_32x32x16_f16(kh, qh[ks], sA, 0, 0, 0);
      sB = __builtin_amdgcn_mfma_f32_32x32x16_f16(kh, ql[ks], sB, 0, 0, 0);
      sB = __builtin_amdgcn_mfma_f32_32x32x16_f16(kl, qh[ks], sB, 0, 0, 0);
    }
    float p[16];
    float tmax = -3e38f;
    const bool diag = (t == qt);
#pragma unroll
    for (int r = 0; r < 16; ++r) {
      const int kvr = (r & 3) + 8 * (r >> 2) + 4 * hi;  // C/D row map (measured)
      float sv = (sA[r] + sB[r]) * 0.125f;              // 1/sqrt(64)
      if (diag && kvr > l31) sv = -1e30f;               // causal mask
      p[r] = sv;
      tmax = fmaxf(tmax, sv);
    }
    tmax = fmaxf(tmax, __shfl_xor(tmax, 32, 64));
    const float mnew = fmaxf(m, tmax);
    const float alpha = __expf(m - mnew);
    float tsum = 0.0f;
#pragma unroll
    for (int r = 0; r < 16; ++r) { p[r] = __expf(p[r] - mnew); tsum += p[r]; }
    tsum += __shfl_xor(tsum, 32, 64);
    l = l * alpha + tsum;
    m = mnew;
    po0 = po0 * alpha;
    po1 = po1 * alpha;
    // pack P to fp16 pairs; exchange halves across lane^32 to build B-frags
    unsigned int pw[8], qw[8];
#pragma unroll
    for (int g = 0; g < 8; ++g) pw[g] = pack2(p[2 * g], p[2 * g + 1]);
#pragma unroll
    for (int g = 0; g < 8; ++g) qw[g] = (unsigned int)__shfl_xor((int)pw[g], 32, 64);
#pragma unroll
    for (int cks = 0; cks < 2; ++cks) {
      union { unsigned int u[4]; h8 v; } bp;
      if (hi == 0) {
        bp.u[0] = pw[4 * cks];     bp.u[1] = pw[4 * cks + 1];
        bp.u[2] = qw[4 * cks];     bp.u[3] = qw[4 * cks + 1];
      } else {
        bp.u[0] = qw[4 * cks + 2]; bp.u[1] = qw[4 * cks + 3];
        bp.u[2] = pw[4 * cks + 2]; bp.u[3] = pw[4 * cks + 3];
      }
      const size_t voff = vbase + (size_t)l31 * S_LEN + c0 + cks * 16 + hi * 8;
      const h8 vh0 = *(const h8*)&Vthi[voff];
      const h8 vl0 = *(const h8*)&Vtlo[voff];
      const h8 vh1 = *(const h8*)&Vthi[voff + (size_t)32 * S_LEN];
      const h8 vl1 = *(const h8*)&Vtlo[voff + (size_t)32 * S_LEN];
      po0 = __builtin_amdgcn_mfma_f32_32x32x16_f16(vh0, bp.v, po0, 0, 0, 0);
      po0 = __builtin_amdgcn_mfma_f32_32x32x16_f16(vl0, bp.v, po0, 0, 0, 0);
      po1 = __builtin_amdgcn_mfma_f32_32x32x16_f16(vh1, bp.v, po1, 0, 0, 0);
      po1 = __builtin_amdgcn_mfma_f32_32x32x16_f16(vl1, bp.v, po1, 0, 0, 0);
    }
  }
  __shared__ float lds_o[32 * 65];
  const float invl = 1.0f / l;
#pragma unroll
  for (int r = 0; r < 16; ++r) {
    const int dl = (r & 3) + 8 * (r >> 2) + 4 * hi;
    lds_o[l31 * 65 + dl] = po0[r] * invl;
    lds_o[l31 * 65 + 32 + dl] = po1[r] * invl;
  }
  __syncthreads();
  const size_t ob = ((size_t)b * S_LEN + q0) * DM + h * DK;
  for (int r2 = 0; r2 < 32; ++r2) {
    O[ob + (size_t)r2 * DM + lane] = lds_o[r2 * 65 + lane];
  }
}

extern "C" void kernel_launch(void* const* d_in, const int* in_sizes, int n_in,
                              void* d_out, int out_size, void* d_ws, size_t ws_size,
                              hipStream_t stream) {
  const float* q   = (const float*)d_in[0];
  const float* k   = (const float*)d_in[1];
  const float* v   = (const float*)d_in[2];
  // d_in[3] = causal mask, implemented analytically
  const float* w_q = (const float*)d_in[4];
  const float* b_q = (const float*)d_in[5];
  const float* w_k = (const float*)d_in[6];
  const float* b_k = (const float*)d_in[7];
  const float* w_v = (const float*)d_in[8];
  const float* b_v = (const float*)d_in[9];
  const float* w_o = (const float*)d_in[10];
  const float* b_o = (const float*)d_in[11];

  char* ws = (char*)d_ws;
  const size_t SZH = (size_t)8192 * 1024 * sizeof(_Float16);  // 16.78 MB
  _Float16* Qhi  = (_Float16*)(ws + 0 * SZH);
  _Float16* Qlo  = (_Float16*)(ws + 1 * SZH);
  _Float16* Khi  = (_Float16*)(ws + 2 * SZH);
  _Float16* Klo  = (_Float16*)(ws + 3 * SZH);
  _Float16* Vthi = (_Float16*)(ws + 4 * SZH);
  _Float16* Vtlo = (_Float16*)(ws + 5 * SZH);
  float*    Vp   = (float*)(ws + 6 * SZH);  // 33.5 MB (2*SZH)
  float*    Oa   = Vp;                      // alias: Vp dead after vtrans

  dim3 gg(64, 8);
  gemm_xwT<0><<<gg, 256, 0, stream>>>(q, w_q, b_q, Qhi, Qlo, nullptr);
  gemm_xwT<0><<<gg, 256, 0, stream>>>(k, w_k, b_k, Khi, Klo, nullptr);
  gemm_xwT<1><<<gg, 256, 0, stream>>>(v, w_v, b_v, nullptr, nullptr, Vp);
  mha_vtrans<<<dim3(32, 64), 256, 0, stream>>>(Vp, Vthi, Vtlo);
  mha_attn<<<dim3(64, 64), 64, 0, stream>>>(Qhi, Qlo, Khi, Klo, Vthi, Vtlo, Oa);
  gemm_xwT<1><<<gg, 256, 0, stream>>>(Oa, w_o, b_o, nullptr, nullptr, (float*)d_out);
}

// Round 5
// 641.890 us; speedup vs baseline: 1.3854x; 1.3854x over previous
//
#include <hip/hip_runtime.h>

// MHA block for MI355X, v3.
// presplit(fp32->hi/lo fp16) once per array ; gemm via global_load_lds staging
// (zero conversion VALU in K-loop) ; flash attention (paired q-tiles,
// reg-prefetch, swapped QK^T) writes hi/lo ; O-proj same presplit GEMM.

typedef _Float16 h8 __attribute__((ext_vector_type(8)));
typedef float f32x4 __attribute__((ext_vector_type(4)));
typedef float f32x16 __attribute__((ext_vector_type(16)));

#define S_LEN 2048
#define DM 1024
#define DK 64

struct H2 { _Float16 h, l; };
__device__ __forceinline__ H2 split2(float v) {
  H2 r; r.h = (_Float16)v; r.l = (_Float16)(v - (float)r.h); return r;
}
__device__ __forceinline__ unsigned int pack2(float a, float b) {
  union { _Float16 h[2]; unsigned int u; } x;
  x.h[0] = (_Float16)a; x.h[1] = (_Float16)b;
  return x.u;
}

#define GLOAD16(gp, lp)                                                        \
  __builtin_amdgcn_global_load_lds(                                            \
      (const __attribute__((address_space(1))) void*)(gp),                     \
      (__attribute__((address_space(3))) void*)(lp), 16, 0, 0)

// fp32 -> (hi, lo) fp16 planes, 8 elements/thread.
__global__ __launch_bounds__(256)
void presplit(const float* __restrict__ X, _Float16* __restrict__ Hi,
              _Float16* __restrict__ Lo, int n8) {
  const int i = blockIdx.x * 256 + threadIdx.x;
  if (i >= n8) return;
  const float4 a = ((const float4*)X)[2 * i];
  const float4 b = ((const float4*)X)[2 * i + 1];
  h8 hv, lv;
  H2 s;
  s = split2(a.x); hv[0] = s.h; lv[0] = s.l;
  s = split2(a.y); hv[1] = s.h; lv[1] = s.l;
  s = split2(a.z); hv[2] = s.h; lv[2] = s.l;
  s = split2(a.w); hv[3] = s.h; lv[3] = s.l;
  s = split2(b.x); hv[4] = s.h; lv[4] = s.l;
  s = split2(b.y); hv[5] = s.h; lv[5] = s.l;
  s = split2(b.z); hv[6] = s.h; lv[6] = s.l;
  s = split2(b.w); hv[7] = s.h; lv[7] = s.l;
  *(h8*)&Hi[(size_t)i * 8] = hv;
  *(h8*)&Lo[(size_t)i * 8] = lv;
}

// Y[8192,1024] = X @ W^T + bias, X/W pre-split hi/lo fp16 [rows][1024].
// 128x128 tile, BK=32, 4 waves; staging via global_load_lds (16B, linear LDS).
// OUT_MODE 0: write hi/lo fp16 pair; 1: write fp32.
template<int OUT_MODE>
__global__ __launch_bounds__(256)
void gemm_ps(const _Float16* __restrict__ Xhi, const _Float16* __restrict__ Xlo,
             const _Float16* __restrict__ Whi, const _Float16* __restrict__ Wlo,
             const float* __restrict__ bias,
             _Float16* __restrict__ Yhi, _Float16* __restrict__ Ylo,
             float* __restrict__ Yf) {
  __shared__ _Float16 Ah[128 * 32], Al[128 * 32], Bh[128 * 32], Bl[128 * 32];
  const int tid = threadIdx.x;
  const int m0 = blockIdx.x * 128, n0 = blockIdx.y * 128;
  const int wid = tid >> 6, lane = tid & 63;
  const int wm = (wid >> 1) * 64, wn = (wid & 1) * 64;
  const int l15 = lane & 15, lg = lane >> 4;
  // staging role: wave 0->Ah, 1->Al, 2->Bh, 3->Bl
  const _Float16* gsrc = (wid == 0) ? Xhi : (wid == 1) ? Xlo : (wid == 2) ? Whi : Wlo;
  _Float16* lbase = (wid == 0) ? Ah : (wid == 1) ? Al : (wid == 2) ? Bh : Bl;
  const int rbase = (wid < 2) ? m0 : n0;
  const int rowoff = lane >> 2, coloff = (lane & 3) * 8;
  f32x4 acc[4][4] = {};
  for (int kt = 0; kt < 32; ++kt) {
    const int k0 = kt * 32;
#pragma unroll
    for (int c = 0; c < 8; ++c) {
      GLOAD16(&gsrc[(size_t)(rbase + c * 16 + rowoff) * DM + k0 + coloff],
              &lbase[c * 512]);
    }
    __syncthreads();  // drains vmcnt -> LDS tiles complete
    h8 a_h[4], a_l[4], b_h[4], b_l[4];
#pragma unroll
    for (int i = 0; i < 4; ++i) {
      const int ra = (wm + i * 16 + l15) * 32 + lg * 8;
      const int rb = (wn + i * 16 + l15) * 32 + lg * 8;
      a_h[i] = *(const h8*)&Ah[ra];
      a_l[i] = *(const h8*)&Al[ra];
      b_h[i] = *(const h8*)&Bh[rb];
      b_l[i] = *(const h8*)&Bl[rb];
    }
#pragma unroll
    for (int mi = 0; mi < 4; ++mi)
#pragma unroll
      for (int ni = 0; ni < 4; ++ni) {
        acc[mi][ni] = __builtin_amdgcn_mfma_f32_16x16x32_f16(a_h[mi], b_h[ni], acc[mi][ni], 0, 0, 0);
        acc[mi][ni] = __builtin_amdgcn_mfma_f32_16x16x32_f16(a_h[mi], b_l[ni], acc[mi][ni], 0, 0, 0);
        acc[mi][ni] = __builtin_amdgcn_mfma_f32_16x16x32_f16(a_l[mi], b_h[ni], acc[mi][ni], 0, 0, 0);
      }
    __syncthreads();
  }
#pragma unroll
  for (int mi = 0; mi < 4; ++mi)
#pragma unroll
    for (int ni = 0; ni < 4; ++ni)
#pragma unroll
      for (int j = 0; j < 4; ++j) {
        const int rg = m0 + wm + mi * 16 + lg * 4 + j;  // C/D: row=(lane>>4)*4+reg
        const int cg = n0 + wn + ni * 16 + l15;         // col=lane&15
        const float v = acc[mi][ni][j] + bias[cg];
        if constexpr (OUT_MODE == 0) {
          H2 s = split2(v);
          Yhi[(size_t)rg * DM + cg] = s.h;
          Ylo[(size_t)rg * DM + cg] = s.l;
        } else {
          Yf[(size_t)rg * DM + cg] = v;
        }
      }
}

// Vp [B*S, DM] f32 -> Vt hi/lo [bh][d(64)][s(2048)] fp16
__global__ __launch_bounds__(256)
void mha_vtrans(const float* __restrict__ Vp,
                _Float16* __restrict__ Vthi, _Float16* __restrict__ Vtlo) {
  __shared__ float tile[64 * 65];
  const int bh = blockIdx.y, s0 = blockIdx.x * 64;
  const int b = bh >> 4, h = bh & 15;
  const int t = threadIdx.x;
  const int row = t >> 2, cg = (t & 3) * 16;
  const size_t inbase = ((size_t)(b * S_LEN + s0 + row)) * DM + h * DK + cg;
#pragma unroll
  for (int i = 0; i < 4; ++i) {
    const float4 v = *(const float4*)&Vp[inbase + i * 4];
    tile[row * 65 + cg + i * 4 + 0] = v.x;
    tile[row * 65 + cg + i * 4 + 1] = v.y;
    tile[row * 65 + cg + i * 4 + 2] = v.z;
    tile[row * 65 + cg + i * 4 + 3] = v.w;
  }
  __syncthreads();
  const int drow = t >> 2, sg = (t & 3) * 16;
  h8 hv0, hv1, lv0, lv1;
#pragma unroll
  for (int i = 0; i < 8; ++i) {
    H2 a = split2(tile[(sg + i) * 65 + drow]);
    hv0[i] = a.h; lv0[i] = a.l;
    H2 c = split2(tile[(sg + 8 + i) * 65 + drow]);
    hv1[i] = c.h; lv1[i] = c.l;
  }
  const size_t ob = ((size_t)bh * DK + drow) * S_LEN + s0 + sg;
  *(h8*)&Vthi[ob] = hv0;
  *(h8*)&Vthi[ob + 8] = hv1;
  *(h8*)&Vtlo[ob] = lv0;
  *(h8*)&Vtlo[ob + 8] = lv1;
}

// Flash attention v2: 1 wave per PAIR of q-tiles (r, 63-r) -> uniform 65
// iters/wave (causal balance), shared K/V tile loads, K reg double-buffer
// prefetch. Swapped QK^T; online softmax in-register; PV via A=V^T.
// Output written as hi/lo fp16 (feeds presplit O-proj GEMM).
__global__ __launch_bounds__(64)
void mha_attn(const _Float16* __restrict__ Qhi, const _Float16* __restrict__ Qlo,
              const _Float16* __restrict__ Khi, const _Float16* __restrict__ Klo,
              const _Float16* __restrict__ Vthi, const _Float16* __restrict__ Vtlo,
              _Float16* __restrict__ Ohi, _Float16* __restrict__ Olo) {
  const int lane = threadIdx.x;
  const int l31 = lane & 31, hi = lane >> 5;
  // bijective chunked XCD swizzle: XCD x -> heads [8x, 8x+8)
  const int hwid = blockIdx.x + (blockIdx.y << 5);        // grid (32,64)
  const int logical = (hwid & 7) * 256 + (hwid >> 3);
  const int r = logical & 31;                             // near q-tile
  const int bh = logical >> 5;
  const int fq = 63 - r;                                  // far q-tile
  const int b = bh >> 4, h = bh & 15;
  const size_t rowbase = (size_t)b * S_LEN * DM + h * DK;
  const size_t vbase = (size_t)bh * DK * S_LEN;

  h8 qh_r[4], ql_r[4], qh_f[4], ql_f[4];
#pragma unroll
  for (int ks = 0; ks < 4; ++ks) {
    const size_t offr = rowbase + (size_t)(r * 32 + l31) * DM + ks * 16 + hi * 8;
    const size_t offf = rowbase + (size_t)(fq * 32 + l31) * DM + ks * 16 + hi * 8;
    qh_r[ks] = *(const h8*)&Qhi[offr]; ql_r[ks] = *(const h8*)&Qlo[offr];
    qh_f[ks] = *(const h8*)&Qhi[offf]; ql_f[ks] = *(const h8*)&Qlo[offf];
  }
  f32x16 po0r = {}, po1r = {}, po0f = {}, po1f = {};
  float m_r = -1e30f, l_r = 0.0f, m_f = -1e30f, l_f = 0.0f;

  auto loadK = [&](int t, h8 (&kh)[4], h8 (&kl)[4]) {
    const int c0 = t * 32;
#pragma unroll
    for (int ks = 0; ks < 4; ++ks) {
      const size_t koff = rowbase + (size_t)(c0 + l31) * DM + ks * 16 + hi * 8;
      kh[ks] = *(const h8*)&Khi[koff];
      kl[ks] = *(const h8*)&Klo[koff];
    }
  };

  auto smax_pv = [&](const f32x16& sA, const f32x16& sB, bool diag,
                     float& m, float& l, f32x16& po0, f32x16& po1,
                     const h8 (&vh)[2][2], const h8 (&vl)[2][2]) {
    float p[16];
    float tmax = -3e38f;
#pragma unroll
    for (int rr = 0; rr < 16; ++rr) {
      const int kvr = (rr & 3) + 8 * (rr >> 2) + 4 * hi;  // C/D row map (measured)
      float sv = (sA[rr] + sB[rr]) * 0.125f;              // 1/sqrt(64)
      if (diag && kvr > l31) sv = -1e30f;                 // causal mask
      p[rr] = sv;
      tmax = fmaxf(tmax, sv);
    }
    tmax = fmaxf(tmax, __shfl_xor(tmax, 32, 64));
    const float mnew = fmaxf(m, tmax);
    const float alpha = __expf(m - mnew);
    float tsum = 0.0f;
#pragma unroll
    for (int rr = 0; rr < 16; ++rr) { p[rr] = __expf(p[rr] - mnew); tsum += p[rr]; }
    tsum += __shfl_xor(tsum, 32, 64);
    l = l * alpha + tsum;
    m = mnew;
    po0 = po0 * alpha;
    po1 = po1 * alpha;
    unsigned int pw[8], qw[8];
#pragma unroll
    for (int g = 0; g < 8; ++g) pw[g] = pack2(p[2 * g], p[2 * g + 1]);
#pragma unroll
    for (int g = 0; g < 8; ++g) qw[g] = (unsigned int)__shfl_xor((int)pw[g], 32, 64);
#pragma unroll
    for (int cks = 0; cks < 2; ++cks) {
      union { unsigned int u[4]; h8 v; } bp;
      if (hi == 0) {
        bp.u[0] = pw[4 * cks];     bp.u[1] = pw[4 * cks + 1];
        bp.u[2] = qw[4 * cks];     bp.u[3] = qw[4 * cks + 1];
      } else {
        bp.u[0] = qw[4 * cks + 2]; bp.u[1] = qw[4 * cks + 3];
        bp.u[2] = pw[4 * cks + 2]; bp.u[3] = pw[4 * cks + 3];
      }
      po0 = __builtin_amdgcn_mfma_f32_32x32x16_f16(vh[cks][0], bp.v, po0, 0, 0, 0);
      po0 = __builtin_amdgcn_mfma_f32_32x32x16_f16(vl[cks][0], bp.v, po0, 0, 0, 0);
      po1 = __builtin_amdgcn_mfma_f32_32x32x16_f16(vh[cks][1], bp.v, po1, 0, 0, 0);
      po1 = __builtin_amdgcn_mfma_f32_32x32x16_f16(vl[cks][1], bp.v, po1, 0, 0, 0);
    }
  };

  auto body = [&](int t, const h8 (&kh)[4], const h8 (&kl)[4],
                  h8 (&nkh)[4], h8 (&nkl)[4]) {
    if (t + 1 <= fq) loadK(t + 1, nkh, nkl);  // prefetch next K tile
    const int c0 = t * 32;
    h8 vh[2][2], vl[2][2];
#pragma unroll
    for (int cks = 0; cks < 2; ++cks) {
      const size_t voff = vbase + (size_t)l31 * S_LEN + c0 + cks * 16 + hi * 8;
      vh[cks][0] = *(const h8*)&Vthi[voff];
      vl[cks][0] = *(const h8*)&Vtlo[voff];
      vh[cks][1] = *(const h8*)&Vthi[voff + (size_t)32 * S_LEN];
      vl[cks][1] = *(const h8*)&Vtlo[voff + (size_t)32 * S_LEN];
    }
    {  // far q-tile (always active: t <= fq by loop bound)
      f32x16 sA = {}, sB = {};
#pragma unroll
      for (int ks = 0; ks < 4; ++ks) {
        sA = __builtin_amdgcn_mfma_f32_32x32x16_f16(kh[ks], qh_f[ks], sA, 0, 0, 0);
        sB = __builtin_amdgcn_mfma_f32_32x32x16_f16(kh[ks], ql_f[ks], sB, 0, 0, 0);
        sB = __builtin_amdgcn_mfma_f32_32x32x16_f16(kl[ks], qh_f[ks], sB, 0, 0, 0);
      }
      smax_pv(sA, sB, t == fq, m_f, l_f, po0f, po1f, vh, vl);
    }
    if (t <= r) {  // near q-tile
      f32x16 sA = {}, sB = {};
#pragma unroll
      for (int ks = 0; ks < 4; ++ks) {
        sA = __builtin_amdgcn_mfma_f32_32x32x16_f16(kh[ks], qh_r[ks], sA, 0, 0, 0);
        sB = __builtin_amdgcn_mfma_f32_32x32x16_f16(kh[ks], ql_r[ks], sB, 0, 0, 0);
        sB = __builtin_amdgcn_mfma_f32_32x32x16_f16(kl[ks], qh_r[ks], sB, 0, 0, 0);
      }
      smax_pv(sA, sB, t == r, m_r, l_r, po0r, po1r, vh, vl);
    }
  };

  h8 khA[4], klA[4], khB[4], klB[4];
  loadK(0, khA, klA);
  int t = 0;
  while (true) {
    body(t, khA, klA, khB, klB);
    ++t; if (t > fq) break;
    body(t, khB, klB, khA, klA);
    ++t; if (t > fq) break;
  }

  __shared__ float lds_o[32 * 65];
  auto writeO = [&](int qt, float l, const f32x16& po0, const f32x16& po1) {
    const float invl = 1.0f / l;
#pragma unroll
    for (int rr = 0; rr < 16; ++rr) {
      const int dl = (rr & 3) + 8 * (rr >> 2) + 4 * hi;
      lds_o[l31 * 65 + dl] = po0[rr] * invl;
      lds_o[l31 * 65 + 32 + dl] = po1[rr] * invl;
    }
    __syncthreads();
    const size_t ob = ((size_t)b * S_LEN + qt * 32) * DM + h * DK;
    for (int r2 = 0; r2 < 32; ++r2) {
      H2 s = split2(lds_o[r2 * 65 + lane]);
      Ohi[ob + (size_t)r2 * DM + lane] = s.h;
      Olo[ob + (size_t)r2 * DM + lane] = s.l;
    }
    __syncthreads();
  };
  writeO(fq, l_f, po0f, po1f);
  writeO(r, l_r, po0r, po1r);
}

extern "C" void kernel_launch(void* const* d_in, const int* in_sizes, int n_in,
                              void* d_out, int out_size, void* d_ws, size_t ws_size,
                              hipStream_t stream) {
  const float* q   = (const float*)d_in[0];
  const float* k   = (const float*)d_in[1];
  const float* v   = (const float*)d_in[2];
  // d_in[3] = causal mask, implemented analytically
  const float* w_q = (const float*)d_in[4];
  const float* b_q = (const float*)d_in[5];
  const float* w_k = (const float*)d_in[6];
  const float* b_k = (const float*)d_in[7];
  const float* w_v = (const float*)d_in[8];
  const float* b_v = (const float*)d_in[9];
  const float* w_o = (const float*)d_in[10];
  const float* b_o = (const float*)d_in[11];

  const size_t NIN = (size_t)8192 * 1024;      // input/activation elements
  const size_t NW  = (size_t)1024 * 1024;      // weight elements
  const size_t SZH = NIN * sizeof(_Float16);   // 16.78 MB
  char* ws = (char*)d_ws;
  // 4 x 33.55 MB buffers = 134.2 MB total workspace
  _Float16* b1 = (_Float16*)(ws + 0 * SZH);    // X-split / Vt hi+lo
  _Float16* b2 = (_Float16*)(ws + 2 * SZH);    // Qp hi+lo ; later wo-split
  _Float16* b3 = (_Float16*)(ws + 4 * SZH);    // Kp hi+lo
  char*     b4 = ws + 6 * SZH;                 // Vp f32 / O hi+lo

  _Float16* Xhi = b1;            _Float16* Xlo = b1 + NIN;
  _Float16* Qph = b2;            _Float16* Qpl = b2 + NIN;
  _Float16* Kph = b3;            _Float16* Kpl = b3 + NIN;
  float*    Vp  = (float*)b4;
  _Float16* Vth = (_Float16*)b1; _Float16* Vtl = (_Float16*)b1 + NIN;
  _Float16* Oh  = (_Float16*)b4; _Float16* Ol  = (_Float16*)b4 + NIN;
  // weight splits: q/k/v weights scratch in d_out (overwritten by O-proj);
  // w_o split in b2 (Qp dead after attention).
  _Float16* Wdh = (_Float16*)d_out; _Float16* Wdl = (_Float16*)d_out + NW;
  _Float16* Woh = (_Float16*)b2;    _Float16* Wol = (_Float16*)b2 + NW;

  const int NIN8 = (int)(NIN / 8), NW8 = (int)(NW / 8);
  dim3 gg(64, 8);

  // Q projection
  presplit<<<4096, 256, 0, stream>>>(q, Xhi, Xlo, NIN8);
  presplit<<<512, 256, 0, stream>>>(w_q, Wdh, Wdl, NW8);
  gemm_ps<0><<<gg, 256, 0, stream>>>(Xhi, Xlo, Wdh, Wdl, b_q, Qph, Qpl, nullptr);
  // K projection
  presplit<<<4096, 256, 0, stream>>>(k, Xhi, Xlo, NIN8);
  presplit<<<512, 256, 0, stream>>>(w_k, Wdh, Wdl, NW8);
  gemm_ps<0><<<gg, 256, 0, stream>>>(Xhi, Xlo, Wdh, Wdl, b_k, Kph, Kpl, nullptr);
  // V projection (fp32 out for transpose)
  presplit<<<4096, 256, 0, stream>>>(v, Xhi, Xlo, NIN8);
  presplit<<<512, 256, 0, stream>>>(w_v, Wdh, Wdl, NW8);
  gemm_ps<1><<<gg, 256, 0, stream>>>(Xhi, Xlo, Wdh, Wdl, b_v, nullptr, nullptr, Vp);
  // V transpose+split (b1's X-split dead)
  mha_vtrans<<<dim3(32, 64), 256, 0, stream>>>(Vp, Vth, Vtl);
  // attention (Vp dead -> O into b4)
  mha_attn<<<dim3(32, 64), 64, 0, stream>>>(Qph, Qpl, Kph, Kpl, Vth, Vtl, Oh, Ol);
  // output projection (Qp dead -> w_o split into b2)
  presplit<<<512, 256, 0, stream>>>(w_o, Woh, Wol, NW8);
  gemm_ps<1><<<gg, 256, 0, stream>>>(Oh, Ol, Woh, Wol, b_o, nullptr, nullptr, (float*)d_out);
}

// Round 6
// 636.400 us; speedup vs baseline: 1.3974x; 1.0086x over previous
//
#include <hip/hip_runtime.h>

// MHA block for MI355X, v4.
// presplit(fp32->hi/lo fp16) ; gemm 2-phase LDS double-buffer (global_load_lds)
// ; flash attention (paired q-tiles, V-before-K-prefetch load order to keep
// K(t+1) in flight across the PV vmcnt wait, defer-max, setprio) ; O-proj GEMM.

typedef _Float16 h8 __attribute__((ext_vector_type(8)));
typedef float f32x4 __attribute__((ext_vector_type(4)));
typedef float f32x16 __attribute__((ext_vector_type(16)));

#define S_LEN 2048
#define DM 1024
#define DK 64

struct H2 { _Float16 h, l; };
__device__ __forceinline__ H2 split2(float v) {
  H2 r; r.h = (_Float16)v; r.l = (_Float16)(v - (float)r.h); return r;
}
__device__ __forceinline__ unsigned int pack2(float a, float b) {
  union { _Float16 h[2]; unsigned int u; } x;
  x.h[0] = (_Float16)a; x.h[1] = (_Float16)b;
  return x.u;
}

#define GLOAD16(gp, lp)                                                        \
  __builtin_amdgcn_global_load_lds(                                            \
      (const __attribute__((address_space(1))) void*)(gp),                     \
      (__attribute__((address_space(3))) void*)(lp), 16, 0, 0)

// fp32 -> (hi, lo) fp16 planes, 8 elements/thread.
__global__ __launch_bounds__(256)
void presplit(const float* __restrict__ X, _Float16* __restrict__ Hi,
              _Float16* __restrict__ Lo, int n8) {
  const int i = blockIdx.x * 256 + threadIdx.x;
  if (i >= n8) return;
  const float4 a = ((const float4*)X)[2 * i];
  const float4 b = ((const float4*)X)[2 * i + 1];
  h8 hv, lv;
  H2 s;
  s = split2(a.x); hv[0] = s.h; lv[0] = s.l;
  s = split2(a.y); hv[1] = s.h; lv[1] = s.l;
  s = split2(a.z); hv[2] = s.h; lv[2] = s.l;
  s = split2(a.w); hv[3] = s.h; lv[3] = s.l;
  s = split2(b.x); hv[4] = s.h; lv[4] = s.l;
  s = split2(b.y); hv[5] = s.h; lv[5] = s.l;
  s = split2(b.z); hv[6] = s.h; lv[6] = s.l;
  s = split2(b.w); hv[7] = s.h; lv[7] = s.l;
  *(h8*)&Hi[(size_t)i * 8] = hv;
  *(h8*)&Lo[(size_t)i * 8] = lv;
}

// Y[8192,1024] = X @ W^T + bias, X/W pre-split hi/lo fp16.
// 128x128 tile, BK=32, 4 waves; 2-phase double-buffered global_load_lds
// staging: stage kt+1 while computing kt; ONE barrier per K-step.
template<int OUT_MODE>
__global__ __launch_bounds__(256)
void gemm_ps(const _Float16* __restrict__ Xhi, const _Float16* __restrict__ Xlo,
             const _Float16* __restrict__ Whi, const _Float16* __restrict__ Wlo,
             const float* __restrict__ bias,
             _Float16* __restrict__ Yhi, _Float16* __restrict__ Ylo,
             float* __restrict__ Yf) {
  __shared__ _Float16 lds[2][4][128 * 32];  // [buf][plane: Ah Al Bh Bl][tile]
  const int tid = threadIdx.x;
  const int m0 = blockIdx.x * 128, n0 = blockIdx.y * 128;
  const int wid = tid >> 6, lane = tid & 63;
  const int wm = (wid >> 1) * 64, wn = (wid & 1) * 64;
  const int l15 = lane & 15, lg = lane >> 4;
  // staging role: wave 0->Ah, 1->Al, 2->Bh, 3->Bl
  const _Float16* gsrc = (wid == 0) ? Xhi : (wid == 1) ? Xlo : (wid == 2) ? Whi : Wlo;
  const int rbase = (wid < 2) ? m0 : n0;
  const int rowoff = lane >> 2, coloff = (lane & 3) * 8;
  f32x4 acc[4][4] = {};

  auto stage = [&](int buf, int kt) {
    const int k0 = kt * 32;
#pragma unroll
    for (int c = 0; c < 8; ++c) {
      GLOAD16(&gsrc[(size_t)(rbase + c * 16 + rowoff) * DM + k0 + coloff],
              &lds[buf][wid][c * 512]);
    }
  };

  stage(0, 0);
  __syncthreads();
  for (int kt = 0; kt < 32; ++kt) {
    const int buf = kt & 1;
    if (kt + 1 < 32) stage(buf ^ 1, kt + 1);  // overlapped with compute below
    h8 a_h[4], a_l[4], b_h[4], b_l[4];
#pragma unroll
    for (int i = 0; i < 4; ++i) {
      const int ra = (wm + i * 16 + l15) * 32 + lg * 8;
      const int rb = (wn + i * 16 + l15) * 32 + lg * 8;
      a_h[i] = *(const h8*)&lds[buf][0][ra];
      a_l[i] = *(const h8*)&lds[buf][1][ra];
      b_h[i] = *(const h8*)&lds[buf][2][rb];
      b_l[i] = *(const h8*)&lds[buf][3][rb];
    }
    __builtin_amdgcn_s_setprio(1);
#pragma unroll
    for (int mi = 0; mi < 4; ++mi)
#pragma unroll
      for (int ni = 0; ni < 4; ++ni) {
        acc[mi][ni] = __builtin_amdgcn_mfma_f32_16x16x32_f16(a_h[mi], b_h[ni], acc[mi][ni], 0, 0, 0);
        acc[mi][ni] = __builtin_amdgcn_mfma_f32_16x16x32_f16(a_h[mi], b_l[ni], acc[mi][ni], 0, 0, 0);
        acc[mi][ni] = __builtin_amdgcn_mfma_f32_16x16x32_f16(a_l[mi], b_h[ni], acc[mi][ni], 0, 0, 0);
      }
    __builtin_amdgcn_s_setprio(0);
    __syncthreads();  // drains vmcnt (next stage) + lgkm; covered by MFMA above
  }
#pragma unroll
  for (int mi = 0; mi < 4; ++mi)
#pragma unroll
    for (int ni = 0; ni < 4; ++ni)
#pragma unroll
      for (int j = 0; j < 4; ++j) {
        const int rg = m0 + wm + mi * 16 + lg * 4 + j;  // C/D: row=(lane>>4)*4+reg
        const int cg = n0 + wn + ni * 16 + l15;         // col=lane&15
        const float v = acc[mi][ni][j] + bias[cg];
        if constexpr (OUT_MODE == 0) {
          H2 s = split2(v);
          Yhi[(size_t)rg * DM + cg] = s.h;
          Ylo[(size_t)rg * DM + cg] = s.l;
        } else {
          Yf[(size_t)rg * DM + cg] = v;
        }
      }
}

// Vp [B*S, DM] f32 -> Vt hi/lo [bh][d(64)][s(2048)] fp16
__global__ __launch_bounds__(256)
void mha_vtrans(const float* __restrict__ Vp,
                _Float16* __restrict__ Vthi, _Float16* __restrict__ Vtlo) {
  __shared__ float tile[64 * 65];
  const int bh = blockIdx.y, s0 = blockIdx.x * 64;
  const int b = bh >> 4, h = bh & 15;
  const int t = threadIdx.x;
  const int row = t >> 2, cg = (t & 3) * 16;
  const size_t inbase = ((size_t)(b * S_LEN + s0 + row)) * DM + h * DK + cg;
#pragma unroll
  for (int i = 0; i < 4; ++i) {
    const float4 v = *(const float4*)&Vp[inbase + i * 4];
    tile[row * 65 + cg + i * 4 + 0] = v.x;
    tile[row * 65 + cg + i * 4 + 1] = v.y;
    tile[row * 65 + cg + i * 4 + 2] = v.z;
    tile[row * 65 + cg + i * 4 + 3] = v.w;
  }
  __syncthreads();
  const int drow = t >> 2, sg = (t & 3) * 16;
  h8 hv0, hv1, lv0, lv1;
#pragma unroll
  for (int i = 0; i < 8; ++i) {
    H2 a = split2(tile[(sg + i) * 65 + drow]);
    hv0[i] = a.h; lv0[i] = a.l;
    H2 c = split2(tile[(sg + 8 + i) * 65 + drow]);
    hv1[i] = c.h; lv1[i] = c.l;
  }
  const size_t ob = ((size_t)bh * DK + drow) * S_LEN + s0 + sg;
  *(h8*)&Vthi[ob] = hv0;
  *(h8*)&Vthi[ob + 8] = hv1;
  *(h8*)&Vtlo[ob] = lv0;
  *(h8*)&Vtlo[ob + 8] = lv1;
}

// Flash attention v3: paired q-tiles (r, 63-r); V(t) loads issued FIRST, then
// K(t+1) prefetch (vmcnt is FIFO: PV's wait-for-V leaves K(t+1) in flight).
// Swapped QK^T; online softmax with defer-max (THR=8); setprio around MFMA.
__global__ __launch_bounds__(64)
void mha_attn(const _Float16* __restrict__ Qhi, const _Float16* __restrict__ Qlo,
              const _Float16* __restrict__ Khi, const _Float16* __restrict__ Klo,
              const _Float16* __restrict__ Vthi, const _Float16* __restrict__ Vtlo,
              _Float16* __restrict__ Ohi, _Float16* __restrict__ Olo) {
  const int lane = threadIdx.x;
  const int l31 = lane & 31, hi = lane >> 5;
  // bijective chunked XCD swizzle: XCD x -> heads [8x, 8x+8)
  const int hwid = blockIdx.x + (blockIdx.y << 5);        // grid (32,64)
  const int logical = (hwid & 7) * 256 + (hwid >> 3);
  const int r = logical & 31;                             // near q-tile
  const int bh = logical >> 5;
  const int fq = 63 - r;                                  // far q-tile
  const int b = bh >> 4, h = bh & 15;
  const size_t rowbase = (size_t)b * S_LEN * DM + h * DK;
  const size_t vbase = (size_t)bh * DK * S_LEN;

  h8 qh_r[4], ql_r[4], qh_f[4], ql_f[4];
#pragma unroll
  for (int ks = 0; ks < 4; ++ks) {
    const size_t offr = rowbase + (size_t)(r * 32 + l31) * DM + ks * 16 + hi * 8;
    const size_t offf = rowbase + (size_t)(fq * 32 + l31) * DM + ks * 16 + hi * 8;
    qh_r[ks] = *(const h8*)&Qhi[offr]; ql_r[ks] = *(const h8*)&Qlo[offr];
    qh_f[ks] = *(const h8*)&Qhi[offf]; ql_f[ks] = *(const h8*)&Qlo[offf];
  }
  f32x16 po0r = {}, po1r = {}, po0f = {}, po1f = {};
  float m_r = -1e30f, l_r = 0.0f, m_f = -1e30f, l_f = 0.0f;

  auto loadK = [&](int t, h8 (&kh)[4], h8 (&kl)[4]) {
    const int c0 = t * 32;
#pragma unroll
    for (int ks = 0; ks < 4; ++ks) {
      const size_t koff = rowbase + (size_t)(c0 + l31) * DM + ks * 16 + hi * 8;
      kh[ks] = *(const h8*)&Khi[koff];
      kl[ks] = *(const h8*)&Klo[koff];
    }
  };

  auto smax_pv = [&](const f32x16& sA, const f32x16& sB, bool diag,
                     float& m, float& l, f32x16& po0, f32x16& po1,
                     const h8 (&vh)[2][2], const h8 (&vl)[2][2]) {
    float p[16];
    float tmax = -3e38f;
#pragma unroll
    for (int rr = 0; rr < 16; ++rr) {
      const int kvr = (rr & 3) + 8 * (rr >> 2) + 4 * hi;  // C/D row map (measured)
      float sv = (sA[rr] + sB[rr]) * 0.125f;              // 1/sqrt(64)
      if (diag && kvr > l31) sv = -1e30f;                 // causal mask
      p[rr] = sv;
      tmax = fmaxf(tmax, sv);
    }
    tmax = fmaxf(tmax, __shfl_xor(tmax, 32, 64));
    // defer-max (T13): rescale only when max grew past THR=8
    if (!__all(tmax <= m + 8.0f)) {
      const float mnew = fmaxf(m, tmax);
      const float alpha = __expf(m - mnew);
      l *= alpha;
      po0 = po0 * alpha;
      po1 = po1 * alpha;
      m = mnew;
    }
    float tsum = 0.0f;
#pragma unroll
    for (int rr = 0; rr < 16; ++rr) { p[rr] = __expf(p[rr] - m); tsum += p[rr]; }
    tsum += __shfl_xor(tsum, 32, 64);
    l += tsum;
    unsigned int pw[8], qw[8];
#pragma unroll
    for (int g = 0; g < 8; ++g) pw[g] = pack2(p[2 * g], p[2 * g + 1]);
#pragma unroll
    for (int g = 0; g < 8; ++g) qw[g] = (unsigned int)__shfl_xor((int)pw[g], 32, 64);
    __builtin_amdgcn_s_setprio(1);
#pragma unroll
    for (int cks = 0; cks < 2; ++cks) {
      union { unsigned int u[4]; h8 v; } bp;
      if (hi == 0) {
        bp.u[0] = pw[4 * cks];     bp.u[1] = pw[4 * cks + 1];
        bp.u[2] = qw[4 * cks];     bp.u[3] = qw[4 * cks + 1];
      } else {
        bp.u[0] = qw[4 * cks + 2]; bp.u[1] = qw[4 * cks + 3];
        bp.u[2] = pw[4 * cks + 2]; bp.u[3] = pw[4 * cks + 3];
      }
      po0 = __builtin_amdgcn_mfma_f32_32x32x16_f16(vh[cks][0], bp.v, po0, 0, 0, 0);
      po0 = __builtin_amdgcn_mfma_f32_32x32x16_f16(vl[cks][0], bp.v, po0, 0, 0, 0);
      po1 = __builtin_amdgcn_mfma_f32_32x32x16_f16(vh[cks][1], bp.v, po1, 0, 0, 0);
      po1 = __builtin_amdgcn_mfma_f32_32x32x16_f16(vl[cks][1], bp.v, po1, 0, 0, 0);
    }
    __builtin_amdgcn_s_setprio(0);
  };

  auto body = [&](int t, const h8 (&kh)[4], const h8 (&kl)[4],
                  h8 (&nkh)[4], h8 (&nkl)[4]) {
    const int c0 = t * 32;
    // V(t) loads FIRST (oldest in vmcnt FIFO among this iter's issues)
    h8 vh[2][2], vl[2][2];
#pragma unroll
    for (int cks = 0; cks < 2; ++cks) {
      const size_t voff = vbase + (size_t)l31 * S_LEN + c0 + cks * 16 + hi * 8;
      vh[cks][0] = *(const h8*)&Vthi[voff];
      vl[cks][0] = *(const h8*)&Vtlo[voff];
      vh[cks][1] = *(const h8*)&Vthi[voff + (size_t)32 * S_LEN];
      vl[cks][1] = *(const h8*)&Vtlo[voff + (size_t)32 * S_LEN];
    }
    // K(t+1) prefetch AFTER V: PV's wait-for-V leaves these in flight
    if (t + 1 <= fq) loadK(t + 1, nkh, nkl);
    {  // far q-tile (always active: t <= fq by loop bound)
      f32x16 sA = {}, sB = {};
      __builtin_amdgcn_s_setprio(1);
#pragma unroll
      for (int ks = 0; ks < 4; ++ks) {
        sA = __builtin_amdgcn_mfma_f32_32x32x16_f16(kh[ks], qh_f[ks], sA, 0, 0, 0);
        sB = __builtin_amdgcn_mfma_f32_32x32x16_f16(kh[ks], ql_f[ks], sB, 0, 0, 0);
        sB = __builtin_amdgcn_mfma_f32_32x32x16_f16(kl[ks], qh_f[ks], sB, 0, 0, 0);
      }
      __builtin_amdgcn_s_setprio(0);
      smax_pv(sA, sB, t == fq, m_f, l_f, po0f, po1f, vh, vl);
    }
    if (t <= r) {  // near q-tile
      f32x16 sA = {}, sB = {};
      __builtin_amdgcn_s_setprio(1);
#pragma unroll
      for (int ks = 0; ks < 4; ++ks) {
        sA = __builtin_amdgcn_mfma_f32_32x32x16_f16(kh[ks], qh_r[ks], sA, 0, 0, 0);
        sB = __builtin_amdgcn_mfma_f32_32x32x16_f16(kh[ks], ql_r[ks], sB, 0, 0, 0);
        sB = __builtin_amdgcn_mfma_f32_32x32x16_f16(kl[ks], qh_r[ks], sB, 0, 0, 0);
      }
      __builtin_amdgcn_s_setprio(0);
      smax_pv(sA, sB, t == r, m_r, l_r, po0r, po1r, vh, vl);
    }
  };

  h8 khA[4], klA[4], khB[4], klB[4];
  loadK(0, khA, klA);
  int t = 0;
  while (true) {
    body(t, khA, klA, khB, klB);
    ++t; if (t > fq) break;
    body(t, khB, klB, khA, klA);
    ++t; if (t > fq) break;
  }

  __shared__ float lds_o[32 * 65];
  auto writeO = [&](int qt, float l, const f32x16& po0, const f32x16& po1) {
    const float invl = 1.0f / l;
#pragma unroll
    for (int rr = 0; rr < 16; ++rr) {
      const int dl = (rr & 3) + 8 * (rr >> 2) + 4 * hi;
      lds_o[l31 * 65 + dl] = po0[rr] * invl;
      lds_o[l31 * 65 + 32 + dl] = po1[rr] * invl;
    }
    __syncthreads();
    const size_t ob = ((size_t)b * S_LEN + qt * 32) * DM + h * DK;
    for (int r2 = 0; r2 < 32; ++r2) {
      H2 s = split2(lds_o[r2 * 65 + lane]);
      Ohi[ob + (size_t)r2 * DM + lane] = s.h;
      Olo[ob + (size_t)r2 * DM + lane] = s.l;
    }
    __syncthreads();
  };
  writeO(fq, l_f, po0f, po1f);
  writeO(r, l_r, po0r, po1r);
}

extern "C" void kernel_launch(void* const* d_in, const int* in_sizes, int n_in,
                              void* d_out, int out_size, void* d_ws, size_t ws_size,
                              hipStream_t stream) {
  const float* q   = (const float*)d_in[0];
  const float* k   = (const float*)d_in[1];
  const float* v   = (const float*)d_in[2];
  // d_in[3] = causal mask, implemented analytically
  const float* w_q = (const float*)d_in[4];
  const float* b_q = (const float*)d_in[5];
  const float* w_k = (const float*)d_in[6];
  const float* b_k = (const float*)d_in[7];
  const float* w_v = (const float*)d_in[8];
  const float* b_v = (const float*)d_in[9];
  const float* w_o = (const float*)d_in[10];
  const float* b_o = (const float*)d_in[11];

  const size_t NIN = (size_t)8192 * 1024;      // input/activation elements
  const size_t NW  = (size_t)1024 * 1024;      // weight elements
  const size_t SZH = NIN * sizeof(_Float16);   // 16.78 MB
  char* ws = (char*)d_ws;
  // 4 x 33.55 MB buffers = 134.2 MB total workspace
  _Float16* b1 = (_Float16*)(ws + 0 * SZH);    // X-split / Vt hi+lo
  _Float16* b2 = (_Float16*)(ws + 2 * SZH);    // Qp hi+lo ; later wo-split
  _Float16* b3 = (_Float16*)(ws + 4 * SZH);    // Kp hi+lo
  char*     b4 = ws + 6 * SZH;                 // Vp f32 / O hi+lo

  _Float16* Xhi = b1;            _Float16* Xlo = b1 + NIN;
  _Float16* Qph = b2;            _Float16* Qpl = b2 + NIN;
  _Float16* Kph = b3;            _Float16* Kpl = b3 + NIN;
  float*    Vp  = (float*)b4;
  _Float16* Vth = (_Float16*)b1; _Float16* Vtl = (_Float16*)b1 + NIN;
  _Float16* Oh  = (_Float16*)b4; _Float16* Ol  = (_Float16*)b4 + NIN;
  // weight splits: q/k/v weights scratch in d_out (overwritten by O-proj);
  // w_o split in b2 (Qp dead after attention).
  _Float16* Wdh = (_Float16*)d_out; _Float16* Wdl = (_Float16*)d_out + NW;
  _Float16* Woh = (_Float16*)b2;    _Float16* Wol = (_Float16*)b2 + NW;

  const int NIN8 = (int)(NIN / 8), NW8 = (int)(NW / 8);
  dim3 gg(64, 8);

  // Q projection
  presplit<<<4096, 256, 0, stream>>>(q, Xhi, Xlo, NIN8);
  presplit<<<512, 256, 0, stream>>>(w_q, Wdh, Wdl, NW8);
  gemm_ps<0><<<gg, 256, 0, stream>>>(Xhi, Xlo, Wdh, Wdl, b_q, Qph, Qpl, nullptr);
  // K projection
  presplit<<<4096, 256, 0, stream>>>(k, Xhi, Xlo, NIN8);
  presplit<<<512, 256, 0, stream>>>(w_k, Wdh, Wdl, NW8);
  gemm_ps<0><<<gg, 256, 0, stream>>>(Xhi, Xlo, Wdh, Wdl, b_k, Kph, Kpl, nullptr);
  // V projection (fp32 out for transpose)
  presplit<<<4096, 256, 0, stream>>>(v, Xhi, Xlo, NIN8);
  presplit<<<512, 256, 0, stream>>>(w_v, Wdh, Wdl, NW8);
  gemm_ps<1><<<gg, 256, 0, stream>>>(Xhi, Xlo, Wdh, Wdl, b_v, nullptr, nullptr, Vp);
  // V transpose+split (b1's X-split dead)
  mha_vtrans<<<dim3(32, 64), 256, 0, stream>>>(Vp, Vth, Vtl);
  // attention (Vp dead -> O into b4)
  mha_attn<<<dim3(32, 64), 64, 0, stream>>>(Qph, Qpl, Kph, Kpl, Vth, Vtl, Oh, Ol);
  // output projection (Qp dead -> w_o split into b2)
  presplit<<<512, 256, 0, stream>>>(w_o, Woh, Wol, NW8);
  gemm_ps<1><<<gg, 256, 0, stream>>>(Oh, Ol, Woh, Wol, b_o, nullptr, nullptr, (float*)d_out);
}